// Round 6
// baseline (543.972 us; speedup 1.0000x reference)
//
#include <hip/hip_runtime.h>
#include <hip/hip_bf16.h>
#include <math.h>

// Problem constants: B=512, L=128, D=512, H=8, HD=64
// M = B*L = 65536, K = D = 512, N_qkv = 3D = 1536.

typedef __attribute__((ext_vector_type(4))) float f32x4;
typedef __attribute__((ext_vector_type(8))) short bf16x8;

__device__ __forceinline__ unsigned short f2bf(float f) {
  union { float f; unsigned u; } x; x.f = f;
  return (unsigned short)((x.u + 0x7FFFu + ((x.u >> 16) & 1u)) >> 16);
}

__device__ __forceinline__ void gload16(const void* g, void* l) {
  __builtin_amdgcn_global_load_lds((const __attribute__((address_space(1))) void*)g,
                                   (__attribute__((address_space(3))) void*)l, 16, 0, 0);
}

// ---------------- f32 -> bf16 convert ----------------
__global__ void cvt_f32_bf16(const float* __restrict__ in,
                             unsigned short* __restrict__ out, int n8) {
  int i = blockIdx.x * blockDim.x + threadIdx.x;
  if (i >= n8) return;
  const float4* p = (const float4*)in + (size_t)i * 2;
  float4 a = p[0], b = p[1];
  union { bf16x8 v; short s[8]; } o;
  o.s[0] = (short)f2bf(a.x); o.s[1] = (short)f2bf(a.y);
  o.s[2] = (short)f2bf(a.z); o.s[3] = (short)f2bf(a.w);
  o.s[4] = (short)f2bf(b.x); o.s[5] = (short)f2bf(b.y);
  o.s[6] = (short)f2bf(b.z); o.s[7] = (short)f2bf(b.w);
  *(bf16x8*)(out + (size_t)i * 8) = o.v;
}

// ---------------- QKV GEMM  C = A @ Bt^T (m97 structure, unchanged) ----------
template <int MODE, int NBX>
__global__ __launch_bounds__(256, 3) void gemm_lds(
    const unsigned short* __restrict__ A, const unsigned short* __restrict__ Bt,
    unsigned short* __restrict__ Cb, float* __restrict__ Cf,
    const float* __restrict__ bias, const float* __restrict__ resid, int ldC) {
  __shared__ __align__(16) unsigned short As[128 * 64];
  __shared__ __align__(16) unsigned short Bs[128 * 64];
  const int t = threadIdx.x;
  const int w = t >> 6, lane = t & 63;
  const int wr = w >> 1, wc = w & 1;
  const int g = lane >> 4, l16 = lane & 15;
  const int bid = blockIdx.x;
  const int cpx = (int)(gridDim.x >> 3);
  const int nid = (bid & 7) * cpx + (bid >> 3);
  const long rowBase = (long)(nid / NBX) * 128;
  const long colBase = (long)(nid % NBX) * 128;

  f32x4 acc[4][4] = {};

  for (int k0 = 0; k0 < 512; k0 += 64) {
#pragma unroll
    for (int i = 0; i < 4; ++i) {
      int flat = i * 256 + t;
      int row = flat >> 3;
      int c8 = ((flat & 7) ^ (row & 7)) << 3;
      gload16(A + (rowBase + row) * 512 + k0 + c8, (char*)As + flat * 16);
      gload16(Bt + (colBase + row) * 512 + k0 + c8, (char*)Bs + flat * 16);
    }
    __syncthreads();
#pragma unroll
    for (int kk = 0; kk < 2; ++kk) {
      bf16x8 af[4], bfr[4];
#pragma unroll
      for (int fm = 0; fm < 4; ++fm) {
        int r = wr * 64 + fm * 16 + l16;
        af[fm] = *(const bf16x8*)((char*)As + r * 128 + ((kk * 64 + g * 16) ^ ((r & 7) << 4)));
      }
#pragma unroll
      for (int fn = 0; fn < 4; ++fn) {
        int r = wc * 64 + fn * 16 + l16;
        bfr[fn] = *(const bf16x8*)((char*)Bs + r * 128 + ((kk * 64 + g * 16) ^ ((r & 7) << 4)));
      }
#pragma unroll
      for (int fm = 0; fm < 4; ++fm)
#pragma unroll
        for (int fn = 0; fn < 4; ++fn)
          acc[fm][fn] = __builtin_amdgcn_mfma_f32_16x16x32_bf16(af[fm], bfr[fn], acc[fm][fn], 0, 0, 0);
    }
    __syncthreads();
  }

#pragma unroll
  for (int fm = 0; fm < 4; ++fm) {
#pragma unroll
    for (int fn = 0; fn < 4; ++fn) {
      long col = colBase + wc * 64 + fn * 16 + l16;
      float bcol = bias[col];
#pragma unroll
      for (int r = 0; r < 4; ++r) {
        long row = rowBase + wr * 64 + fm * 16 + g * 4 + r;
        float v = acc[fm][fn][r] + bcol;
        if constexpr (MODE == 0) {
          if (col < 512) v *= 0.125f;
          Cb[row * ldC + col] = f2bf(v);
        } else {
          Cf[row * ldC + col] = v + resid[row * ldC + col];
        }
      }
    }
  }
}

// ---------------- fused out-proj + bias + residual + LayerNorm ---------------
// 1024 thr = 16 waves (2x8), wave tile 64x64, acc[4][4]=64 VGPR -> 4 waves/SIMD.
// BM=128 rows, BN=512 (full row), BK=64.
__global__ __launch_bounds__(1024, 1) void oproj_ln(
    const unsigned short* __restrict__ Ab, const unsigned short* __restrict__ Wt,
    const float* __restrict__ x, const float* __restrict__ bout,
    const float* __restrict__ lnw, const float* __restrict__ lnb,
    float* __restrict__ out) {
  __shared__ __align__(16) unsigned short As[128 * 64];
  __shared__ __align__(16) unsigned short Bs[512 * 64];
  __shared__ float ps[128][8], pq[128][8], mus[128], rss[128];
  const int t = threadIdx.x;
  const int w = t >> 6, lane = t & 63;
  const int wr = w >> 3, wc = w & 7;
  const int g = lane >> 4, l16 = lane & 15;
  const long rowBase = (long)blockIdx.x * 128;

  f32x4 acc[4][4] = {};

  for (int k0 = 0; k0 < 512; k0 += 64) {
    {
      int flat = t;
      int row = flat >> 3;
      int c8 = ((flat & 7) ^ (row & 7)) << 3;
      gload16(Ab + (rowBase + row) * 512 + k0 + c8, (char*)As + flat * 16);
    }
#pragma unroll
    for (int i = 0; i < 4; ++i) {
      int flat = i * 1024 + t;
      int row = flat >> 3;
      int c8 = ((flat & 7) ^ (row & 7)) << 3;
      gload16(Wt + row * 512 + k0 + c8, (char*)Bs + flat * 16);
    }
    __syncthreads();
#pragma unroll
    for (int kk = 0; kk < 2; ++kk) {
      bf16x8 af[4], bfr[4];
#pragma unroll
      for (int fm = 0; fm < 4; ++fm) {
        int r = wr * 64 + fm * 16 + l16;
        af[fm] = *(const bf16x8*)((char*)As + r * 128 + ((kk * 64 + g * 16) ^ ((r & 7) << 4)));
      }
#pragma unroll
      for (int fn = 0; fn < 4; ++fn) {
        int n = wc * 64 + fn * 16 + l16;
        bfr[fn] = *(const bf16x8*)((char*)Bs + n * 128 + ((kk * 64 + g * 16) ^ ((n & 7) << 4)));
      }
#pragma unroll
      for (int fm = 0; fm < 4; ++fm)
#pragma unroll
        for (int fn = 0; fn < 4; ++fn)
          acc[fm][fn] = __builtin_amdgcn_mfma_f32_16x16x32_bf16(af[fm], bfr[fn], acc[fm][fn], 0, 0, 0);
    }
    __syncthreads();
  }

  // h = acc + bias + resid; per-row partial sums (this wave's 64 cols) to LDS
  float bo[4];
#pragma unroll
  for (int fn = 0; fn < 4; ++fn) bo[fn] = bout[wc * 64 + fn * 16 + l16];

#pragma unroll
  for (int fm = 0; fm < 4; ++fm) {
#pragma unroll
    for (int r = 0; r < 4; ++r) {
      const int rloc = wr * 64 + fm * 16 + g * 4 + r;
      const long row = rowBase + rloc;
      float sh = 0.f, sq = 0.f;
#pragma unroll
      for (int fn = 0; fn < 4; ++fn) {
        int col = wc * 64 + fn * 16 + l16;
        float h = acc[fm][fn][r] + bo[fn] + x[row * 512 + col];
        acc[fm][fn][r] = h;
        sh += h;
        sq += h * h;
      }
#pragma unroll
      for (int off = 1; off < 16; off <<= 1) {
        sh += __shfl_xor(sh, off);
        sq += __shfl_xor(sq, off);
      }
      if (l16 == 0) {
        ps[rloc][wc] = sh;
        pq[rloc][wc] = sq;
      }
    }
  }
  __syncthreads();
  if (t < 128) {
    float s = 0.f, q = 0.f;
#pragma unroll
    for (int c = 0; c < 8; ++c) { s += ps[t][c]; q += pq[t][c]; }
    float mu = s * (1.0f / 512.0f);
    float var = q * (1.0f / 512.0f) - mu * mu;
    mus[t] = mu;
    rss[t] = rsqrtf(var + 1e-5f);
  }
  __syncthreads();

  float lw[4], lb[4];
#pragma unroll
  for (int fn = 0; fn < 4; ++fn) {
    lw[fn] = lnw[wc * 64 + fn * 16 + l16];
    lb[fn] = lnb[wc * 64 + fn * 16 + l16];
  }
#pragma unroll
  for (int fm = 0; fm < 4; ++fm) {
#pragma unroll
    for (int r = 0; r < 4; ++r) {
      const int rloc = wr * 64 + fm * 16 + g * 4 + r;
      const long row = rowBase + rloc;
      const float mu = mus[rloc], rs = rss[rloc];
#pragma unroll
      for (int fn = 0; fn < 4; ++fn) {
        int col = wc * 64 + fn * 16 + l16;
        out[row * 512 + col] = (acc[fm][fn][r] - mu) * rs * lw[fn] + lb[fn];
      }
    }
  }
}

// ---------------- attention per (b, h) ----------------
// Per-fm restructure: QK^T / softmax / PV per 16-row half -> accS[8] only,
// Pl halved to [4][16*136]. LDS 50.5 KB -> 3 blocks/CU.
__global__ __launch_bounds__(256, 3) void attn_kernel(
    const unsigned short* __restrict__ qkv, const float* __restrict__ corr,
    const int* __restrict__ mask, const float* __restrict__ bias_scale,
    unsigned short* __restrict__ o) {
  __shared__ __align__(16) unsigned short kt[128 * 64];
  __shared__ __align__(16) unsigned short Pl[4][16 * 136];
  __shared__ __align__(16) unsigned short vt[64 * 136];
  __shared__ float biasl[128];
  const int t = threadIdx.x;
  const int w = t >> 6, lane = t & 63;
  const int g = lane >> 4, l16 = lane & 15;
  const int b = blockIdx.x >> 3, h = blockIdx.x & 7;
  const long qkvBase = (long)b * 128 * 1536;

  // K -> LDS (swizzled source, linear dest)
#pragma unroll
  for (int i = 0; i < 4; ++i) {
    int flat = i * 256 + t;
    int row = flat >> 3;
    int c8 = ((flat & 7) ^ (row & 7)) << 3;
    gload16(qkv + qkvBase + (long)row * 1536 + 512 + h * 64 + c8, (char*)kt + flat * 16);
  }

  // stage V^T : vt[d][s] = v[s][d]
#pragma unroll
  for (int i = 0; i < 4; ++i) {
    int q = t + i * 256;
    int row = q >> 3, c8 = q & 7;
    union { bf16x8 v; unsigned short s[8]; } u;
    u.v = *(const bf16x8*)(qkv + qkvBase + (long)row * 1536 + 1024 + h * 64 + c8 * 8);
#pragma unroll
    for (int j = 0; j < 8; ++j) vt[(c8 * 8 + j) * 136 + row] = u.s[j];
  }
  if (t < 128) {
    float bs = bias_scale[0];
    biasl[t] = mask[b * 128 + t] ? -INFINITY : bs * corr[b * 128 + t];
  }

  // q fragments direct from global
  bf16x8 aq[2][2];
#pragma unroll
  for (int fm = 0; fm < 2; ++fm)
#pragma unroll
    for (int kk = 0; kk < 2; ++kk)
      aq[fm][kk] = *(const bf16x8*)(qkv + qkvBase + (long)(w * 32 + fm * 16 + l16) * 1536 + h * 64 + kk * 32 + g * 8);

  __syncthreads();  // kt (DMA), vt, biasl ready

  float bv[8];
#pragma unroll
  for (int fn = 0; fn < 8; ++fn) bv[fn] = biasl[fn * 16 + l16];

  const long oBase = (long)b * 128 * 512 + (long)h * 64;

#pragma unroll
  for (int fm = 0; fm < 2; ++fm) {
    // S-half = q[fm] @ k^T
    f32x4 accS[8] = {};
#pragma unroll
    for (int fn = 0; fn < 8; ++fn) {
      int r = fn * 16 + l16;
      bf16x8 bk0 = *(const bf16x8*)((char*)kt + r * 128 + ((g * 16) ^ ((r & 7) << 4)));
      bf16x8 bk1 = *(const bf16x8*)((char*)kt + r * 128 + ((64 + g * 16) ^ ((r & 7) << 4)));
      accS[fn] = __builtin_amdgcn_mfma_f32_16x16x32_bf16(aq[fm][0], bk0, accS[fn], 0, 0, 0);
      accS[fn] = __builtin_amdgcn_mfma_f32_16x16x32_bf16(aq[fm][1], bk1, accS[fn], 0, 0, 0);
    }

    // softmax over s (cols) for the 16 rows of this half
    float rinv[4];
#pragma unroll
    for (int r = 0; r < 4; ++r) {
      float m = -INFINITY;
#pragma unroll
      for (int fn = 0; fn < 8; ++fn) m = fmaxf(m, accS[fn][r] + bv[fn]);
#pragma unroll
      for (int off = 1; off < 16; off <<= 1) m = fmaxf(m, __shfl_xor(m, off));
      float s = 0.f;
#pragma unroll
      for (int fn = 0; fn < 8; ++fn) {
        float p = __expf(accS[fn][r] + bv[fn] - m);
        accS[fn][r] = p;
        s += p;
      }
#pragma unroll
      for (int off = 1; off < 16; off <<= 1) s += __shfl_xor(s, off);
      rinv[r] = 1.0f / s;
#pragma unroll
      for (int fn = 0; fn < 8; ++fn)
        Pl[w][(g * 4 + r) * 136 + fn * 16 + l16] = f2bf(accS[fn][r]);
    }

    // O-half = P @ V (wave-private Pl half; in-wave LDS ordering)
    f32x4 accO[4] = {};
#pragma unroll
    for (int kk = 0; kk < 4; ++kk) {
      bf16x8 ap = *(const bf16x8*)&Pl[w][l16 * 136 + kk * 32 + g * 8];
#pragma unroll
      for (int fn = 0; fn < 4; ++fn) {
        bf16x8 bw = *(const bf16x8*)&vt[(fn * 16 + l16) * 136 + kk * 32 + g * 8];
        accO[fn] = __builtin_amdgcn_mfma_f32_16x16x32_bf16(ap, bw, accO[fn], 0, 0, 0);
      }
    }

#pragma unroll
    for (int fn = 0; fn < 4; ++fn)
#pragma unroll
      for (int r = 0; r < 4; ++r)
        o[oBase + (long)(w * 32 + fm * 16 + g * 4 + r) * 512 + fn * 16 + l16] =
            f2bf(accO[fn][r] * rinv[r]);
  }
}

extern "C" void kernel_launch(void* const* d_in, const int* in_sizes, int n_in,
                              void* d_out, int out_size, void* d_ws, size_t ws_size,
                              hipStream_t stream) {
  const float* x = (const float*)d_in[0];
  const float* corr = (const float*)d_in[1];
  const int* mask = (const int*)d_in[2];
  const float* w_in = (const float*)d_in[3];
  const float* b_in = (const float*)d_in[4];
  const float* w_out = (const float*)d_in[5];
  const float* b_out = (const float*)d_in[6];
  const float* ln_w = (const float*)d_in[7];
  const float* ln_b = (const float*)d_in[8];
  const float* bscale = (const float*)d_in[9];

  unsigned short* wqkv_bf = (unsigned short*)d_ws;              // 786432
  unsigned short* wout_bf = wqkv_bf + 786432;                   // 262144
  unsigned short* qkv = wout_bf + 262144;                       // 65536*1536
  unsigned short* xb_ob = qkv + (size_t)65536 * 1536;           // 65536*512 (xb then ob)

  cvt_f32_bf16<<<dim3(384), dim3(256), 0, stream>>>(w_in, wqkv_bf, 98304);
  cvt_f32_bf16<<<dim3(128), dim3(256), 0, stream>>>(w_out, wout_bf, 32768);
  cvt_f32_bf16<<<dim3(16384), dim3(256), 0, stream>>>(x, xb_ob, 4194304);

  gemm_lds<0, 12><<<dim3(6144), dim3(256), 0, stream>>>(
      xb_ob, wqkv_bf, qkv, (float*)nullptr, b_in, (const float*)nullptr, 1536);

  attn_kernel<<<dim3(4096), dim3(256), 0, stream>>>(qkv, corr, mask, bscale, xb_ob);

  oproj_ln<<<dim3(512), dim3(1024), 0, stream>>>(
      xb_ob, wout_bf, x, b_out, ln_w, ln_b, (float*)d_out);
}